// Round 6
// baseline (28.085 us; speedup 1.0000x reference)
//
#include <hip/hip_runtime.h>

// SeparateSourceDense: out[n,:] = x[n,:] @ kernel[source[n]] + bias[source[n],:]
// N=8192, F=256, OUT=256, S=16.
// Round 6: r5 structure, but B fragments load DIRECTLY global->VGPR (16 B
// contiguous per lane in Wt[o][f] layout) issued before the scan so their
// latency hides under it. b_lds + its staging phase + one sync removed.
//   K1 wtrans_k: W [s][f][o] fp32 -> Wt [s][o][f] bf16 (unchanged)
//   K2 mfma_gemm_k: 768 blocks (16s x 12mc x 4n0), 256 thr, in-block scan,
//      A in LDS (33 KB), B in regs, 16x16x32 bf16 MFMA.

#define NROWS 8192
#define FDIM  256
#define ODIM  256
#define NSRC  16

#define BM 64
#define BN 64
#define LDA 264          // LDS row stride (shorts): 528 B, 16B-aligned
#define MCHUNKS 12       // covers cnt_s <= 768 (mean 512, sigma ~22)
#define NWG (NSRC * MCHUNKS * 4)   // 768

typedef float f32x4 __attribute__((ext_vector_type(4)));
typedef short s16x8 __attribute__((ext_vector_type(8)));

__device__ __forceinline__ uint f2bf(float f) {
    union { float f; uint u; } v; v.f = f;              // RNE, inputs finite
    return (v.u + 0x7fffu + ((v.u >> 16) & 1u)) >> 16;
}
__device__ __forceinline__ uint pk2(float lo, float hi) {
    return f2bf(lo) | (f2bf(hi) << 16);
}

// ---------------------------------------------------------------------------
// K1: transpose+convert W[s][f][o] (fp32) -> Wt[s][o][f] (bf16).
// ---------------------------------------------------------------------------
__global__ __launch_bounds__(256) void wtrans_k(const float* __restrict__ kern,
                                                ushort* __restrict__ wt) {
    __shared__ float tile[64][65];
    const int s  = blockIdx.x;
    const int fi = (blockIdx.y & 3) * 64;
    const int oi = (blockIdx.y >> 2) * 64;
    const int t  = threadIdx.x;
    const int r0 = t >> 4;
    const int c4 = (t & 15) * 4;
    const float* src = kern + (size_t)(s * FDIM + fi + r0) * ODIM + oi + c4;
    #pragma unroll
    for (int j = 0; j < 4; ++j) {
        const float4 v = *(const float4*)(src + (size_t)j * 16 * ODIM);
        tile[r0 + j * 16][c4 + 0] = v.x;
        tile[r0 + j * 16][c4 + 1] = v.y;
        tile[r0 + j * 16][c4 + 2] = v.z;
        tile[r0 + j * 16][c4 + 3] = v.w;
    }
    __syncthreads();
    const int f4 = (t & 15) * 4;
    #pragma unroll
    for (int j = 0; j < 4; ++j) {
        const int o_loc = (t >> 4) + j * 16;
        ushort4 u;
        u.x = (ushort)f2bf(tile[f4 + 0][o_loc]);
        u.y = (ushort)f2bf(tile[f4 + 1][o_loc]);
        u.z = (ushort)f2bf(tile[f4 + 2][o_loc]);
        u.w = (ushort)f2bf(tile[f4 + 3][o_loc]);
        *(ushort4*)&wt[(size_t)(s * ODIM + oi + o_loc) * FDIM + fi + f4] = u;
    }
}

// ---------------------------------------------------------------------------
// K2: MFMA grouped GEMM, in-block bucketize, B direct-to-register.
// ---------------------------------------------------------------------------
__global__ __launch_bounds__(256) void mfma_gemm_k(
        const float* __restrict__ x,
        const int* __restrict__ source,
        const ushort* __restrict__ wt,
        const float* __restrict__ bias,
        float* __restrict__ out) {
    // XCD-chunked swizzle: XCD c gets contiguous wg range [c*96, c*96+96)
    const int bid = blockIdx.x;
    const int wg  = (bid & 7) * (NWG / 8) + (bid >> 3);
    const int tile = wg >> 2;
    const int s    = tile / MCHUNKS;
    const int mc   = tile % MCHUNKS;
    const int n0   = (wg & 3) * BN;
    const int lo   = mc * BM;

    const int t    = threadIdx.x;
    const int lane = t & 63;
    const int wid  = t >> 6;

    __shared__ int   wsum[4];
    __shared__ int   rows_lds[BM];
    __shared__ short a_lds[BM * LDA];           // 33 KB

    // wave/fragment coordinates (needed for early B loads)
    const int wr = (wid >> 1) * 32;
    const int wc = (wid & 1) * 32;
    const int lr = lane & 15;
    const int lg = lane >> 4;

    // ---- issue source loads FIRST (scan depends on them) ----
    int4 sv[8];
    const int4* sp = (const int4*)source + (size_t)t * 8;
    #pragma unroll
    for (int i = 0; i < 8; ++i) sv[i] = sp[i];

    // ---- then issue all 16 B-fragment loads (drain during scan) ----
    // b0 frag: Wt row n0+wc+lr, elems 32*kk + 8*lg .. +8 (16 B contiguous)
    // b1 frag: row +16
    const ushort* bp = wt + ((size_t)(s * ODIM + n0 + wc + lr)) * FDIM + 8 * lg;
    s16x8 breg0[8], breg1[8];
    #pragma unroll
    for (int kk = 0; kk < 8; ++kk) {
        breg0[kk] = *(const s16x8*)(bp + 32 * kk);
        breg1[kk] = *(const s16x8*)(bp + 16 * FDIM + 32 * kk);
    }

    // ---- in-block scan: thread t owns rows [32t, 32t+32) ----
    int c = 0;
    #pragma unroll
    for (int i = 0; i < 8; ++i)
        c += (sv[i].x == s) + (sv[i].y == s) + (sv[i].z == s) + (sv[i].w == s);
    int p = c;
    #pragma unroll
    for (int d = 1; d < 64; d <<= 1) {
        const int v = __shfl_up(p, d);
        if (lane >= d) p += v;
    }
    if (lane == 63) wsum[wid] = p;
    __syncthreads();
    int r = p - c;                              // exclusive prefix in wave
    #pragma unroll
    for (int w = 0; w < 4; ++w) if (w < wid) r += wsum[w];
    const int cnt = wsum[0] + wsum[1] + wsum[2] + wsum[3];
    if (cnt <= lo) return;                      // uniform per block
    const int nvalid = min(BM, cnt - lo);

    // scatter this thread's matches landing in [lo, lo+64)
    #pragma unroll
    for (int i = 0; i < 8; ++i) {
        const int base = t * 32 + i * 4;
        if (sv[i].x == s) { if (r >= lo && r < lo + BM) rows_lds[r - lo] = base;     ++r; }
        if (sv[i].y == s) { if (r >= lo && r < lo + BM) rows_lds[r - lo] = base + 1; ++r; }
        if (sv[i].z == s) { if (r >= lo && r < lo + BM) rows_lds[r - lo] = base + 2; ++r; }
        if (sv[i].w == s) { if (r >= lo && r < lo + BM) rows_lds[r - lo] = base + 3; ++r; }
    }
    __syncthreads();

    // ---- stage A: gathered x rows, fp32 -> bf16, clamp padding rows ----
    const int ar = t >> 2;
    const int ac = (t & 3) * 8;
    {
        const float* xrow = x + (size_t)rows_lds[(ar < nvalid) ? ar : 0] * FDIM + ac;
        short* dst = &a_lds[ar * LDA + ac];
        #pragma unroll
        for (int j = 0; j < 8; ++j) {
            const float4 f0 = *(const float4*)(xrow + j * 32);
            const float4 f1 = *(const float4*)(xrow + j * 32 + 4);
            uint4 pk;
            pk.x = pk2(f0.x, f0.y);
            pk.y = pk2(f0.z, f0.w);
            pk.z = pk2(f1.x, f1.y);
            pk.w = pk2(f1.z, f1.w);
            *(uint4*)(dst + j * 32) = pk;
        }
    }
    __syncthreads();

    // ---- MFMA: 4 waves in 2x2, each 32x32 out; B from regs ----
    f32x4 acc00 = {}, acc01 = {}, acc10 = {}, acc11 = {};
    const short* ab = &a_lds[(wr + lr) * LDA + 8 * lg];

    #pragma unroll
    for (int kk = 0; kk < 8; ++kk) {
        const s16x8 a0 = *(const s16x8*)(ab + kk * 32);
        const s16x8 a1 = *(const s16x8*)(ab + kk * 32 + 16 * LDA);
        acc00 = __builtin_amdgcn_mfma_f32_16x16x32_bf16(a0, breg0[kk], acc00, 0, 0, 0);
        acc01 = __builtin_amdgcn_mfma_f32_16x16x32_bf16(a0, breg1[kk], acc01, 0, 0, 0);
        acc10 = __builtin_amdgcn_mfma_f32_16x16x32_bf16(a1, breg0[kk], acc10, 0, 0, 0);
        acc11 = __builtin_amdgcn_mfma_f32_16x16x32_bf16(a1, breg1[kk], acc11, 0, 0, 0);
    }

    // ---- epilogue: D[row=4*lg+r][col=lr]; bias add + row scatter ----
    const float bv0 = bias[s * ODIM + n0 + wc + lr];
    const float bv1 = bias[s * ODIM + n0 + wc + 16 + lr];
    const int col0 = n0 + wc + lr;
    #pragma unroll
    for (int rr = 0; rr < 4; ++rr) {
        int lm = wr + 4 * lg + rr;
        if (lm < nvalid) {
            float* orow = out + (size_t)rows_lds[lm] * ODIM;
            orow[col0]      = acc00[rr] + bv0;
            orow[col0 + 16] = acc01[rr] + bv1;
        }
        lm += 16;
        if (lm < nvalid) {
            float* orow = out + (size_t)rows_lds[lm] * ODIM;
            orow[col0]      = acc10[rr] + bv0;
            orow[col0 + 16] = acc11[rr] + bv1;
        }
    }
}

// ---------------------------------------------------------------------------
extern "C" void kernel_launch(void* const* d_in, const int* in_sizes, int n_in,
                              void* d_out, int out_size, void* d_ws, size_t ws_size,
                              hipStream_t stream) {
    const float* x      = (const float*)d_in[0];
    const int*   source = (const int*)d_in[1];
    const float* kern   = (const float*)d_in[2];
    const float* bias   = (const float*)d_in[3];
    float*       out    = (float*)d_out;

    ushort* wt = (ushort*)d_ws;                 // 2 MB bf16 [16][256][256]

    hipLaunchKernelGGL(wtrans_k, dim3(NSRC, 16), dim3(256), 0, stream, kern, wt);
    hipLaunchKernelGGL(mfma_gemm_k, dim3(NWG), dim3(256), 0, stream,
                       x, source, wt, bias, out);
}

// Round 7
// 22.454 us; speedup vs baseline: 1.2508x; 1.2508x over previous
//
#include <hip/hip_runtime.h>

// SeparateSourceDense: out[n,:] = x[n,:] @ kernel[source[n]] + bias[source[n],:]
// N=8192, F=256, OUT=256, S=16.
// Round 7: ONE fused kernel. Each block: in-block bucketize scan (r5) ->
// transposes its own 64KB W-slice W[s][:,n0:n0+64] fp32->bf16 into b_lds via
// an fp32 LDS tile (wtrans code path, unioned with a_lds) -> stages gathered
// A rows -> 16x16x32 bf16 MFMA -> bias + scatter epilogue.
// No second kernel, no launch gap, no workspace.

#define NROWS 8192
#define FDIM  256
#define ODIM  256
#define NSRC  16

#define BM 64
#define BN 64
#define LDA 264          // LDS row stride (shorts): 528 B, 16B-aligned
#define MCHUNKS 12       // covers cnt_s <= 768 (mean 512, sigma ~22)
#define NWG (NSRC * MCHUNKS * 4)   // 768

typedef float f32x4 __attribute__((ext_vector_type(4)));
typedef short s16x8 __attribute__((ext_vector_type(8)));

__device__ __forceinline__ uint f2bf(float f) {
    union { float f; uint u; } v; v.f = f;              // RNE, inputs finite
    return (v.u + 0x7fffu + ((v.u >> 16) & 1u)) >> 16;
}
__device__ __forceinline__ uint pk2(float lo, float hi) {
    return f2bf(lo) | (f2bf(hi) << 16);
}

__global__ __launch_bounds__(256) void fused_k(
        const float* __restrict__ x,
        const int* __restrict__ source,
        const float* __restrict__ kern,
        const float* __restrict__ bias,
        float* __restrict__ out) {
    // XCD-chunked swizzle: XCD c gets contiguous wg range [c*96, c*96+96)
    const int bid = blockIdx.x;
    const int wg  = (bid & 7) * (NWG / 8) + (bid >> 3);
    const int tile = wg >> 2;
    const int s    = tile / MCHUNKS;
    const int mc   = tile % MCHUNKS;
    const int n0   = (wg & 3) * BN;
    const int lo   = mc * BM;

    const int t    = threadIdx.x;
    const int lane = t & 63;
    const int wid  = t >> 6;

    __shared__ int   wsum[4];
    __shared__ int   rows_lds[BM];
    __shared__ short b_lds[BN * LDA];                   // 33 KB
    // union: fp32 transpose tile [64][65] (16.6 KB) lives strictly before
    // a_lds (33 KB) — disjoint lifetimes, same buffer.
    __shared__ __align__(16) char u_buf[BM * LDA * 2];
    short* a_lds = (short*)u_buf;
    float (*tile_f)[65] = (float (*)[65])u_buf;

    // ---- phase 1: in-block scan (thread t owns rows [32t, 32t+32)) ----
    int4 sv[8];
    const int4* sp = (const int4*)source + (size_t)t * 8;
    #pragma unroll
    for (int i = 0; i < 8; ++i) sv[i] = sp[i];
    int c = 0;
    #pragma unroll
    for (int i = 0; i < 8; ++i)
        c += (sv[i].x == s) + (sv[i].y == s) + (sv[i].z == s) + (sv[i].w == s);
    int p = c;
    #pragma unroll
    for (int d = 1; d < 64; d <<= 1) {
        const int v = __shfl_up(p, d);
        if (lane >= d) p += v;
    }
    if (lane == 63) wsum[wid] = p;
    __syncthreads();
    int r = p - c;                              // exclusive prefix in wave
    #pragma unroll
    for (int w = 0; w < 4; ++w) if (w < wid) r += wsum[w];
    const int cnt = wsum[0] + wsum[1] + wsum[2] + wsum[3];
    if (cnt <= lo) return;                      // uniform: dead block exits
    const int nvalid = min(BM, cnt - lo);

    // scatter this thread's matches landing in [lo, lo+64)
    #pragma unroll
    for (int i = 0; i < 8; ++i) {
        const int base = t * 32 + i * 4;
        if (sv[i].x == s) { if (r >= lo && r < lo + BM) rows_lds[r - lo] = base;     ++r; }
        if (sv[i].y == s) { if (r >= lo && r < lo + BM) rows_lds[r - lo] = base + 1; ++r; }
        if (sv[i].z == s) { if (r >= lo && r < lo + BM) rows_lds[r - lo] = base + 2; ++r; }
        if (sv[i].w == s) { if (r >= lo && r < lo + BM) rows_lds[r - lo] = base + 3; ++r; }
    }
    __syncthreads();                            // publish rows_lds

    // ---- phase 2: issue ALL global loads (W first, then x; vmcnt is
    // issue-ordered, so tile-0 consumption never waits on x) ----
    const int r0 = t >> 4;                      // 0..15
    const int c4 = (t & 15) * 4;                // 0..60
    const float* wbase = kern + ((size_t)s * FDIM + r0) * ODIM + n0 + c4;
    float4 wv[4][4];
    #pragma unroll
    for (int j = 0; j < 4; ++j)
        #pragma unroll
        for (int u = 0; u < 4; ++u)
            wv[j][u] = *(const float4*)(wbase + (size_t)(64 * j + 16 * u) * ODIM);

    const int ar = t >> 2;
    const int ac = (t & 3) * 8;
    const float* xrow = x + (size_t)rows_lds[(ar < nvalid) ? ar : 0] * FDIM + ac;
    float4 xv[16];
    #pragma unroll
    for (int j = 0; j < 8; ++j) {
        xv[2 * j]     = *(const float4*)(xrow + j * 32);
        xv[2 * j + 1] = *(const float4*)(xrow + j * 32 + 4);
    }

    // ---- phase 3: transpose W-slice through fp32 tile into b_lds[o][k] ----
    #pragma unroll
    for (int j = 0; j < 4; ++j) {
        if (j) __syncthreads();                 // tile reuse vs prev reads
        #pragma unroll
        for (int u = 0; u < 4; ++u) {
            tile_f[r0 + 16 * u][c4 + 0] = wv[j][u].x;
            tile_f[r0 + 16 * u][c4 + 1] = wv[j][u].y;
            tile_f[r0 + 16 * u][c4 + 2] = wv[j][u].z;
            tile_f[r0 + 16 * u][c4 + 3] = wv[j][u].w;
        }
        __syncthreads();
        #pragma unroll
        for (int u = 0; u < 4; ++u) {
            const int o_loc = r0 + 16 * u;
            ushort4 q;
            q.x = (ushort)f2bf(tile_f[c4 + 0][o_loc]);
            q.y = (ushort)f2bf(tile_f[c4 + 1][o_loc]);
            q.z = (ushort)f2bf(tile_f[c4 + 2][o_loc]);
            q.w = (ushort)f2bf(tile_f[c4 + 3][o_loc]);
            *(ushort4*)&b_lds[o_loc * LDA + 64 * j + c4] = q;
        }
    }
    __syncthreads();                            // last tile reads done

    // ---- phase 4: write gathered A rows (bf16) into a_lds (aliases tile) ----
    {
        short* dst = &a_lds[ar * LDA + ac];
        #pragma unroll
        for (int j = 0; j < 8; ++j) {
            const float4 f0 = xv[2 * j];
            const float4 f1 = xv[2 * j + 1];
            uint4 pk;
            pk.x = pk2(f0.x, f0.y);
            pk.y = pk2(f0.z, f0.w);
            pk.z = pk2(f1.x, f1.y);
            pk.w = pk2(f1.z, f1.w);
            *(uint4*)(dst + j * 32) = pk;
        }
    }
    __syncthreads();                            // a_lds + b_lds ready

    // ---- phase 5: MFMA, 4 waves in 2x2, each 32x32 out ----
    const int wr = (wid >> 1) * 32;
    const int wc = (wid & 1) * 32;
    const int lr = lane & 15;
    const int lg = lane >> 4;

    f32x4 acc00 = {}, acc01 = {}, acc10 = {}, acc11 = {};
    const short* ab = &a_lds[(wr + lr) * LDA + 8 * lg];
    const short* bb = &b_lds[(wc + lr) * LDA + 8 * lg];

    #pragma unroll 2
    for (int kk = 0; kk < 8; ++kk) {
        const s16x8 a0 = *(const s16x8*)(ab + kk * 32);
        const s16x8 a1 = *(const s16x8*)(ab + kk * 32 + 16 * LDA);
        const s16x8 b0 = *(const s16x8*)(bb + kk * 32);
        const s16x8 b1 = *(const s16x8*)(bb + kk * 32 + 16 * LDA);
        acc00 = __builtin_amdgcn_mfma_f32_16x16x32_bf16(a0, b0, acc00, 0, 0, 0);
        acc01 = __builtin_amdgcn_mfma_f32_16x16x32_bf16(a0, b1, acc01, 0, 0, 0);
        acc10 = __builtin_amdgcn_mfma_f32_16x16x32_bf16(a1, b0, acc10, 0, 0, 0);
        acc11 = __builtin_amdgcn_mfma_f32_16x16x32_bf16(a1, b1, acc11, 0, 0, 0);
    }

    // ---- epilogue: D[row=4*lg+rr][col=lr]; bias add + row scatter ----
    const float bv0 = bias[s * ODIM + n0 + wc + lr];
    const float bv1 = bias[s * ODIM + n0 + wc + 16 + lr];
    const int col0 = n0 + wc + lr;
    #pragma unroll
    for (int rr = 0; rr < 4; ++rr) {
        int lm = wr + 4 * lg + rr;
        if (lm < nvalid) {
            float* orow = out + (size_t)rows_lds[lm] * ODIM;
            orow[col0]      = acc00[rr] + bv0;
            orow[col0 + 16] = acc01[rr] + bv1;
        }
        lm += 16;
        if (lm < nvalid) {
            float* orow = out + (size_t)rows_lds[lm] * ODIM;
            orow[col0]      = acc10[rr] + bv0;
            orow[col0 + 16] = acc11[rr] + bv1;
        }
    }
}

// ---------------------------------------------------------------------------
extern "C" void kernel_launch(void* const* d_in, const int* in_sizes, int n_in,
                              void* d_out, int out_size, void* d_ws, size_t ws_size,
                              hipStream_t stream) {
    const float* x      = (const float*)d_in[0];
    const int*   source = (const int*)d_in[1];
    const float* kern   = (const float*)d_in[2];
    const float* bias   = (const float*)d_in[3];
    float*       out    = (float*)d_out;

    hipLaunchKernelGGL(fused_k, dim3(NWG), dim3(256), 0, stream,
                       x, source, kern, bias, out);
}

// Round 8
// 21.678 us; speedup vs baseline: 1.2956x; 1.0358x over previous
//
#include <hip/hip_runtime.h>

// SeparateSourceDense: out[n,:] = x[n,:] @ kernel[source[n]] + bias[source[n],:]
// N=8192, F=256, OUT=256, S=16.
// Round 8: r7 fused kernel with a shorter critical path:
//   - W loads issued BEFORE the scan (independent; hide under scan/scatter)
//   - transpose fp32 tile double-buffered (syncs 8 -> 5)
//   - grid 16x8x4 = 512 (no statically-dead blocks); cnt>512 overflow handled
//     by an m-loop on the last chunk (rescatter with reloaded sv)

#define NROWS 8192
#define FDIM  256
#define ODIM  256
#define NSRC  16

#define BM 64
#define BN 64
#define LDA 264          // LDS row stride (shorts): 528 B, 16B-aligned
#define MCHUNKS 8
#define NWG (NSRC * MCHUNKS * 4)   // 512
#define TILE_BYTES 16640           // one fp32 [64][65] tile

typedef float f32x4 __attribute__((ext_vector_type(4)));
typedef short s16x8 __attribute__((ext_vector_type(8)));

__device__ __forceinline__ uint f2bf(float f) {
    union { float f; uint u; } v; v.f = f;              // RNE, inputs finite
    return (v.u + 0x7fffu + ((v.u >> 16) & 1u)) >> 16;
}
__device__ __forceinline__ uint pk2(float lo, float hi) {
    return f2bf(lo) | (f2bf(hi) << 16);
}

__global__ __launch_bounds__(256) void fused_k(
        const float* __restrict__ x,
        const int* __restrict__ source,
        const float* __restrict__ kern,
        const float* __restrict__ bias,
        float* __restrict__ out) {
    // XCD-chunked swizzle: XCD c gets contiguous wg range [c*64, c*64+64)
    const int bid = blockIdx.x;
    const int wg  = (bid & 7) * (NWG / 8) + (bid >> 3);
    const int tile = wg >> 2;
    const int s    = tile / MCHUNKS;
    const int mc   = tile % MCHUNKS;
    const int n0   = (wg & 3) * BN;
    const int lo0  = mc * BM;

    const int t    = threadIdx.x;
    const int lane = t & 63;
    const int wid  = t >> 6;

    __shared__ int   wsum[4];
    __shared__ int   rows_lds[BM];
    __shared__ short b_lds[BN * LDA];                   // 33 KB
    // union: two fp32 transpose tiles [64][65] (16.6 KB each), lifetimes
    // strictly before a_lds (33 KB) — same buffer.
    __shared__ __align__(16) char u_buf[BM * LDA * 2];  // 33792 B
    short* a_lds = (short*)u_buf;

    // ---- issue source loads (scan needs them first) ----
    int4 sv[8];
    const int4* sp = (const int4*)source + (size_t)t * 8;
    #pragma unroll
    for (int i = 0; i < 8; ++i) sv[i] = sp[i];

    // ---- issue W loads NOW (independent of scan; drain under scan) ----
    const int r0 = t >> 4;                      // 0..15
    const int c4 = (t & 15) * 4;                // 0..60
    const float* wbase = kern + ((size_t)s * FDIM + r0) * ODIM + n0 + c4;
    float4 wv[4][4];
    #pragma unroll
    for (int j = 0; j < 4; ++j)
        #pragma unroll
        for (int u = 0; u < 4; ++u)
            wv[j][u] = *(const float4*)(wbase + (size_t)(64 * j + 16 * u) * ODIM);

    // ---- scan: thread t owns rows [32t, 32t+32) ----
    int c = 0;
    #pragma unroll
    for (int i = 0; i < 8; ++i)
        c += (sv[i].x == s) + (sv[i].y == s) + (sv[i].z == s) + (sv[i].w == s);
    int p = c;
    #pragma unroll
    for (int d = 1; d < 64; d <<= 1) {
        const int v = __shfl_up(p, d);
        if (lane >= d) p += v;
    }
    if (lane == 63) wsum[wid] = p;
    __syncthreads();
    int r_base = p - c;                         // exclusive prefix in wave
    #pragma unroll
    for (int w = 0; w < 4; ++w) if (w < wid) r_base += wsum[w];
    const int cnt = wsum[0] + wsum[1] + wsum[2] + wsum[3];
    if (cnt <= lo0) return;                     // uniform: rare idle block

    // ---- first scatter (sv dies after this; frees 32 VGPRs) ----
    {
        int r = r_base;
        #pragma unroll
        for (int i = 0; i < 8; ++i) {
            const int base = t * 32 + i * 4;
            if (sv[i].x == s) { if (r >= lo0 && r < lo0 + BM) rows_lds[r - lo0] = base;     ++r; }
            if (sv[i].y == s) { if (r >= lo0 && r < lo0 + BM) rows_lds[r - lo0] = base + 1; ++r; }
            if (sv[i].z == s) { if (r >= lo0 && r < lo0 + BM) rows_lds[r - lo0] = base + 2; ++r; }
            if (sv[i].w == s) { if (r >= lo0 && r < lo0 + BM) rows_lds[r - lo0] = base + 3; ++r; }
        }
    }

    const int ar = t >> 2;
    const int ac = (t & 3) * 8;
    const int wr = (wid >> 1) * 32;
    const int wc = (wid & 1) * 32;
    const int lr = lane & 15;
    const int lg = lane >> 4;

    const float bv0 = bias[s * ODIM + n0 + wc + lr];
    const float bv1 = bias[s * ODIM + n0 + wc + 16 + lr];
    const int col0 = n0 + wc + lr;

    int lo = lo0;
    bool first = true;
    while (true) {
        const int nvalid = min(BM, cnt - lo);
        __syncthreads();                        // rows_lds published

        // issue gathered x loads (consumed after transpose / immediately)
        const float* xrow = x + (size_t)rows_lds[(ar < nvalid) ? ar : 0] * FDIM + ac;
        float4 xv[16];
        #pragma unroll
        for (int j = 0; j < 8; ++j) {
            xv[2 * j]     = *(const float4*)(xrow + j * 32);
            xv[2 * j + 1] = *(const float4*)(xrow + j * 32 + 4);
        }

        if (first) {
            first = false;
            // transpose W-slice via double-buffered fp32 tiles -> b_lds[o][k]
            #pragma unroll
            for (int j = 0; j < 4; ++j) {
                float (*tf)[65] = (float (*)[65])(u_buf + (j & 1) * TILE_BYTES);
                #pragma unroll
                for (int u = 0; u < 4; ++u) {
                    tf[r0 + 16 * u][c4 + 0] = wv[j][u].x;
                    tf[r0 + 16 * u][c4 + 1] = wv[j][u].y;
                    tf[r0 + 16 * u][c4 + 2] = wv[j][u].z;
                    tf[r0 + 16 * u][c4 + 3] = wv[j][u].w;
                }
                __syncthreads();                // write(j) done before read(j)
                #pragma unroll
                for (int u = 0; u < 4; ++u) {
                    const int o_loc = r0 + 16 * u;
                    ushort4 q;
                    q.x = (ushort)f2bf(tf[c4 + 0][o_loc]);
                    q.y = (ushort)f2bf(tf[c4 + 1][o_loc]);
                    q.z = (ushort)f2bf(tf[c4 + 2][o_loc]);
                    q.w = (ushort)f2bf(tf[c4 + 3][o_loc]);
                    *(ushort4*)&b_lds[o_loc * LDA + 64 * j + c4] = q;
                }
                // write(j+1) into the other tile overlaps read(j): disjoint;
                // write(j+2) reuses this tile only after the next sync.
            }
            __syncthreads();                    // tile reads done (a_lds aliases)
        }

        // stage gathered A rows (bf16) into a_lds
        {
            short* dst = &a_lds[ar * LDA + ac];
            #pragma unroll
            for (int j = 0; j < 8; ++j) {
                const float4 f0 = xv[2 * j];
                const float4 f1 = xv[2 * j + 1];
                uint4 pk;
                pk.x = pk2(f0.x, f0.y);
                pk.y = pk2(f0.z, f0.w);
                pk.z = pk2(f1.x, f1.y);
                pk.w = pk2(f1.z, f1.w);
                *(uint4*)(dst + j * 32) = pk;
            }
        }
        __syncthreads();                        // a_lds + b_lds ready

        // MFMA: 4 waves in 2x2, each 32x32 out
        f32x4 acc00 = {}, acc01 = {}, acc10 = {}, acc11 = {};
        const short* ab = &a_lds[(wr + lr) * LDA + 8 * lg];
        const short* bb = &b_lds[(wc + lr) * LDA + 8 * lg];
        #pragma unroll 2
        for (int kk = 0; kk < 8; ++kk) {
            const s16x8 a0 = *(const s16x8*)(ab + kk * 32);
            const s16x8 a1 = *(const s16x8*)(ab + kk * 32 + 16 * LDA);
            const s16x8 b0 = *(const s16x8*)(bb + kk * 32);
            const s16x8 b1 = *(const s16x8*)(bb + kk * 32 + 16 * LDA);
            acc00 = __builtin_amdgcn_mfma_f32_16x16x32_bf16(a0, b0, acc00, 0, 0, 0);
            acc01 = __builtin_amdgcn_mfma_f32_16x16x32_bf16(a0, b1, acc01, 0, 0, 0);
            acc10 = __builtin_amdgcn_mfma_f32_16x16x32_bf16(a1, b0, acc10, 0, 0, 0);
            acc11 = __builtin_amdgcn_mfma_f32_16x16x32_bf16(a1, b1, acc11, 0, 0, 0);
        }

        // epilogue: D[row=4*lg+rr][col=lr]; bias add + row scatter
        #pragma unroll
        for (int rr = 0; rr < 4; ++rr) {
            int lm = wr + 4 * lg + rr;
            if (lm < nvalid) {
                float* orow = out + (size_t)rows_lds[lm] * ODIM;
                orow[col0]      = acc00[rr] + bv0;
                orow[col0 + 16] = acc01[rr] + bv1;
            }
            lm += 16;
            if (lm < nvalid) {
                float* orow = out + (size_t)rows_lds[lm] * ODIM;
                orow[col0]      = acc10[rr] + bv0;
                orow[col0 + 16] = acc11[rr] + bv1;
            }
        }

        // overflow: only the last chunk loops (cnt > 512 is a ~3% tail event)
        lo += BM;
        if (!(mc == MCHUNKS - 1 && lo < cnt)) break;
        __syncthreads();                        // epilogue rows_lds reads done
        {
            int r = r_base;
            #pragma unroll
            for (int i = 0; i < 8; ++i) {
                const int4 s2 = sp[i];          // reload (rare path)
                const int base = t * 32 + i * 4;
                if (s2.x == s) { if (r >= lo && r < lo + BM) rows_lds[r - lo] = base;     ++r; }
                if (s2.y == s) { if (r >= lo && r < lo + BM) rows_lds[r - lo] = base + 1; ++r; }
                if (s2.z == s) { if (r >= lo && r < lo + BM) rows_lds[r - lo] = base + 2; ++r; }
                if (s2.w == s) { if (r >= lo && r < lo + BM) rows_lds[r - lo] = base + 3; ++r; }
            }
        }
    }
}

// ---------------------------------------------------------------------------
extern "C" void kernel_launch(void* const* d_in, const int* in_sizes, int n_in,
                              void* d_out, int out_size, void* d_ws, size_t ws_size,
                              hipStream_t stream) {
    const float* x      = (const float*)d_in[0];
    const int*   source = (const int*)d_in[1];
    const float* kern   = (const float*)d_in[2];
    const float* bias   = (const float*)d_in[3];
    float*       out    = (float*)d_out;

    hipLaunchKernelGGL(fused_k, dim3(NWG), dim3(256), 0, stream,
                       x, source, kern, bias, out);
}